// Round 1
// baseline (174.787 us; speedup 1.0000x reference)
//
#include <hip/hip_runtime.h>
#include <math.h>

// Problem constants (from reference)
constexpr int MM = 50;    // members per group
constexpr int DD = 64;    // embedding dim
constexpr int HH = 16;    // attention hidden
constexpr int PH = 8;     // predict hidden
constexpr int ROWSTRIDE = DD + 1;        // LDS pad: bank = (m+d)%32 -> <=2-way (free)
constexpr int WAVES_PER_BLOCK = 4;

__global__ __launch_bounds__(256) void agree_kernel(
    const int* __restrict__ group_inputs,
    const int* __restrict__ item_inputs,
    const int* __restrict__ member_ids,
    const int* __restrict__ member_lengths,
    const float* __restrict__ user_table,
    const float* __restrict__ item_table,
    const float* __restrict__ group_table,
    const float* __restrict__ att_w1,   // [2D][H] row-major
    const float* __restrict__ att_b1,   // [H]
    const float* __restrict__ att_w2,   // [H]
    const float* __restrict__ att_b2,   // [1]
    const float* __restrict__ pred_w1,  // [3D][8] row-major
    const float* __restrict__ pred_b1,  // [8]
    const float* __restrict__ pred_w2,  // [8]
    const float* __restrict__ pred_b2,  // [1]
    float* __restrict__ out,
    int B)
{
    __shared__ float lds_mem[WAVES_PER_BLOCK][MM * ROWSTRIDE]; // 13000 B/wave
    __shared__ float lds_wt[WAVES_PER_BLOCK][64];

    const int lane = threadIdx.x & 63;
    const int wave = threadIdx.x >> 6;
    const int b = blockIdx.x * WAVES_PER_BLOCK + wave;
    if (b >= B) return;

    // ---- Phase 0: gather member embedding rows into LDS (coalesced 256B rows)
    const int* ids = member_ids + b * MM;          // uniform base
    float* tile = &lds_mem[wave][0];
    #pragma unroll 5
    for (int r = 0; r < MM; ++r) {
        const int id = ids[r];                     // uniform -> s_load
        tile[r * ROWSTRIDE + lane] = user_table[(size_t)id * DD + lane];
    }

    // item embedding, lane-per-dim
    const int item_idx = item_inputs[b];           // uniform
    const float item_d = item_table[(size_t)item_idx * DD + lane];

    // ---- Phase 1a: item contribution c_j = sum_d item[d]*w1[64+d][j]  (once per row)
    float h[HH];
    {
        const float* w1row = att_w1 + (size_t)(DD + lane) * HH; // 64B per lane, coalesced
        #pragma unroll
        for (int j = 0; j < HH; ++j) h[j] = item_d * w1row[j];
        #pragma unroll
        for (int off = 32; off > 0; off >>= 1) {
            #pragma unroll
            for (int j = 0; j < HH; ++j) h[j] += __shfl_xor(h[j], off, 64);
        }
        #pragma unroll
        for (int j = 0; j < HH; ++j) h[j] += att_b1[j];   // uniform scalar loads
    }

    // ---- Phase 1b: member attention MLP, lane-per-member
    const int len = member_lengths[b];             // uniform
    const int mrow = (lane < MM) ? lane : 0;       // clamp idle lanes (avoid LDS OOB)
    const float* myrow = tile + mrow * ROWSTRIDE;

    #pragma unroll 4
    for (int d = 0; d < DD; ++d) {
        const float x = myrow[d];                  // ds_read_b32, <=2-way bank alias
        const float* w1d = att_w1 + (size_t)d * HH; // uniform -> s_load_dwordx16
        #pragma unroll
        for (int j = 0; j < HH; ++j) h[j] = fmaf(x, w1d[j], h[j]);
    }

    float score = att_b2[0];
    #pragma unroll
    for (int j = 0; j < HH; ++j) score = fmaf(fmaxf(h[j], 0.0f), att_w2[j], score);

    const bool valid = (lane < MM) && (lane <= len);
    score = valid ? score : -INFINITY;

    // ---- softmax over members (wave butterfly; >=1 valid lane guaranteed)
    float mx = score;
    #pragma unroll
    for (int off = 32; off > 0; off >>= 1) mx = fmaxf(mx, __shfl_xor(mx, off, 64));
    float e = valid ? __expf(score - mx) : 0.0f;
    float sum = e;
    #pragma unroll
    for (int off = 32; off > 0; off >>= 1) sum += __shfl_xor(sum, off, 64);
    lds_wt[wave][lane] = e / sum;

    // ---- Phase 2: weighted pool g_att[d] + group embedding, lane-per-dim
    float g = 0.0f;
    #pragma unroll 5
    for (int m = 0; m < MM; ++m) {
        // lds_wt read is wave-uniform (broadcast); tile read is stride-1 across lanes
        g = fmaf(lds_wt[wave][m], tile[m * ROWSTRIDE + lane], g);
    }
    const int gid = group_inputs[b];               // uniform
    g += group_table[(size_t)gid * DD + lane];

    // ---- Phase 3: predict MLP  new_e = [g*item, g, item]  (192 -> 8 -> 1)
    const float elem = g * item_d;
    float p[PH];
    {
        const float* pa = pred_w1 + (size_t)lane * PH;            // rows [0,64)
        const float* pb = pred_w1 + (size_t)(DD + lane) * PH;     // rows [64,128)
        const float* pc = pred_w1 + (size_t)(2 * DD + lane) * PH; // rows [128,192)
        #pragma unroll
        for (int j = 0; j < PH; ++j)
            p[j] = fmaf(elem, pa[j], fmaf(g, pb[j], item_d * pc[j]));
    }
    #pragma unroll
    for (int off = 32; off > 0; off >>= 1) {
        #pragma unroll
        for (int j = 0; j < PH; ++j) p[j] += __shfl_xor(p[j], off, 64);
    }

    if (lane == 0) {
        float acc = pred_b2[0];
        #pragma unroll
        for (int j = 0; j < PH; ++j)
            acc = fmaf(fmaxf(p[j] + pred_b1[j], 0.0f), pred_w2[j], acc);
        out[b] = 1.0f / (1.0f + __expf(-acc));
    }
}

extern "C" void kernel_launch(void* const* d_in, const int* in_sizes, int n_in,
                              void* d_out, int out_size, void* d_ws, size_t ws_size,
                              hipStream_t stream) {
    const int*   group_inputs   = (const int*)d_in[0];
    const int*   item_inputs    = (const int*)d_in[1];
    const int*   member_ids     = (const int*)d_in[2];
    const int*   member_lengths = (const int*)d_in[3];
    const float* user_table     = (const float*)d_in[4];
    const float* item_table     = (const float*)d_in[5];
    const float* group_table    = (const float*)d_in[6];
    const float* att_w1         = (const float*)d_in[7];
    const float* att_b1         = (const float*)d_in[8];
    const float* att_w2         = (const float*)d_in[9];
    const float* att_b2         = (const float*)d_in[10];
    const float* pred_w1        = (const float*)d_in[11];
    const float* pred_b1        = (const float*)d_in[12];
    const float* pred_w2        = (const float*)d_in[13];
    const float* pred_b2        = (const float*)d_in[14];
    float* out = (float*)d_out;

    const int B = in_sizes[0];
    const int blocks = (B + WAVES_PER_BLOCK - 1) / WAVES_PER_BLOCK;
    agree_kernel<<<blocks, 256, 0, stream>>>(
        group_inputs, item_inputs, member_ids, member_lengths,
        user_table, item_table, group_table,
        att_w1, att_b1, att_w2, att_b2,
        pred_w1, pred_b1, pred_w2, pred_b2,
        out, B);
}

// Round 2
// 158.901 us; speedup vs baseline: 1.1000x; 1.1000x over previous
//
#include <hip/hip_runtime.h>
#include <math.h>

constexpr int MM = 50;    // members per group
constexpr int DD = 64;    // embedding dim
constexpr int HH = 16;    // attention hidden
constexpr int PH = 8;     // predict hidden
constexpr int WAVES_PER_BLOCK = 4;

__global__ __launch_bounds__(256) void agree_kernel(
    const int* __restrict__ group_inputs,
    const int* __restrict__ item_inputs,
    const int* __restrict__ member_ids,
    const int* __restrict__ member_lengths,
    const float* __restrict__ user_table,
    const float* __restrict__ item_table,
    const float* __restrict__ group_table,
    const float* __restrict__ att_w1,   // [2D][H] row-major
    const float* __restrict__ att_b1,   // [H]
    const float* __restrict__ att_w2,   // [H]
    const float* __restrict__ att_b2,   // [1]
    const float* __restrict__ pred_w1,  // [3D][8] row-major
    const float* __restrict__ pred_b1,  // [8]
    const float* __restrict__ pred_w2,  // [8]
    const float* __restrict__ pred_b2,  // [1]
    float* __restrict__ out,
    int B)
{
    // tiny per-wave broadcast scratch: (weight, id) pairs -> one ds_read2/b64 per pool iter
    __shared__ float lds_wt[WAVES_PER_BLOCK][MM];
    __shared__ int   lds_id[WAVES_PER_BLOCK][MM];

    const int lane = threadIdx.x & 63;
    const int wave = threadIdx.x >> 6;
    const int b = blockIdx.x * WAVES_PER_BLOCK + wave;
    if (b >= B) return;

    // ---- per-lane member id (lane-per-member mapping; clamp idle lanes 50..63)
    const int my_m = (lane < MM) ? lane : (MM - 1);
    const int my_id = member_ids[b * MM + my_m];            // coalesced 200B
    if (lane < MM) lds_id[wave][lane] = my_id;

    // item embedding, lane-per-dim
    const int item_idx = item_inputs[b];                    // uniform -> s_load
    const float item_d = item_table[(size_t)item_idx * DD + lane];

    // ---- Phase 1a: item part of hidden layer, computed once via butterfly reduce
    float h[HH];
    {
        const float* w1row = att_w1 + (size_t)(DD + lane) * HH; // 64B/lane, coalesced
        #pragma unroll
        for (int j = 0; j < HH; ++j) h[j] = item_d * w1row[j];
        #pragma unroll
        for (int off = 32; off > 0; off >>= 1) {
            #pragma unroll
            for (int j = 0; j < HH; ++j) h[j] += __shfl_xor(h[j], off, 64);
        }
        #pragma unroll
        for (int j = 0; j < HH; ++j) h[j] += att_b1[j];     // uniform s_load
    }

    // ---- Phase 1b: member part, lane-per-member, row read direct from global (L2/L3-hot)
    const float* myrow = user_table + (size_t)my_id * DD;
    #pragma unroll 4
    for (int d4 = 0; d4 < DD / 4; ++d4) {
        const float4 x = ((const float4*)myrow)[d4];        // 16B per lane
        const float* w1d = att_w1 + (size_t)(d4 * 4) * HH;  // uniform -> s_load
        #pragma unroll
        for (int j = 0; j < HH; ++j) {
            h[j] = fmaf(x.x, w1d[0 * HH + j], h[j]);
            h[j] = fmaf(x.y, w1d[1 * HH + j], h[j]);
            h[j] = fmaf(x.z, w1d[2 * HH + j], h[j]);
            h[j] = fmaf(x.w, w1d[3 * HH + j], h[j]);
        }
    }

    float score = att_b2[0];
    #pragma unroll
    for (int j = 0; j < HH; ++j) score = fmaf(fmaxf(h[j], 0.0f), att_w2[j], score);

    const int len = member_lengths[b];                      // uniform
    const bool valid = (lane < MM) && (lane <= len);
    score = valid ? score : -INFINITY;

    // ---- softmax over members (wave butterfly; member 0 always valid)
    float mx = score;
    #pragma unroll
    for (int off = 32; off > 0; off >>= 1) mx = fmaxf(mx, __shfl_xor(mx, off, 64));
    float e = valid ? __expf(score - mx) : 0.0f;
    float sum = e;
    #pragma unroll
    for (int off = 32; off > 0; off >>= 1) sum += __shfl_xor(sum, off, 64);
    if (lane < MM) lds_wt[wave][lane] = e / sum;
    __builtin_amdgcn_s_waitcnt(0);  // drain own LDS writes (same wave, no barrier needed)

    // ---- Phase 2: weighted pool, lane-per-dim; only valid members (wt==0 beyond len)
    const int mcnt = (len < MM - 1 ? len : MM - 1) + 1;     // uniform, in [1,50]
    float g = 0.0f;
    #pragma unroll 2
    for (int m = 0; m < mcnt; ++m) {
        const float wm  = lds_wt[wave][m];                  // broadcast
        const int   idm = lds_id[wave][m];                  // broadcast
        g = fmaf(wm, user_table[(size_t)idm * DD + lane], g); // coalesced, L1/L2-hot
    }
    const int gid = group_inputs[b];                        // uniform
    g += group_table[(size_t)gid * DD + lane];

    // ---- Phase 3: predict MLP  new_e = [g*item, g, item] (192 -> 8 -> 1)
    const float elem = g * item_d;
    float p[PH];
    {
        const float* pa = pred_w1 + (size_t)lane * PH;
        const float* pb = pred_w1 + (size_t)(DD + lane) * PH;
        const float* pc = pred_w1 + (size_t)(2 * DD + lane) * PH;
        #pragma unroll
        for (int j = 0; j < PH; ++j)
            p[j] = fmaf(elem, pa[j], fmaf(g, pb[j], item_d * pc[j]));
    }
    #pragma unroll
    for (int off = 32; off > 0; off >>= 1) {
        #pragma unroll
        for (int j = 0; j < PH; ++j) p[j] += __shfl_xor(p[j], off, 64);
    }

    if (lane == 0) {
        float acc = pred_b2[0];
        #pragma unroll
        for (int j = 0; j < PH; ++j)
            acc = fmaf(fmaxf(p[j] + pred_b1[j], 0.0f), pred_w2[j], acc);
        out[b] = 1.0f / (1.0f + __expf(-acc));
    }
}

extern "C" void kernel_launch(void* const* d_in, const int* in_sizes, int n_in,
                              void* d_out, int out_size, void* d_ws, size_t ws_size,
                              hipStream_t stream) {
    const int*   group_inputs   = (const int*)d_in[0];
    const int*   item_inputs    = (const int*)d_in[1];
    const int*   member_ids     = (const int*)d_in[2];
    const int*   member_lengths = (const int*)d_in[3];
    const float* user_table     = (const float*)d_in[4];
    const float* item_table     = (const float*)d_in[5];
    const float* group_table    = (const float*)d_in[6];
    const float* att_w1         = (const float*)d_in[7];
    const float* att_b1         = (const float*)d_in[8];
    const float* att_w2         = (const float*)d_in[9];
    const float* att_b2         = (const float*)d_in[10];
    const float* pred_w1        = (const float*)d_in[11];
    const float* pred_b1        = (const float*)d_in[12];
    const float* pred_w2        = (const float*)d_in[13];
    const float* pred_b2        = (const float*)d_in[14];
    float* out = (float*)d_out;

    const int B = in_sizes[0];
    const int blocks = (B + WAVES_PER_BLOCK - 1) / WAVES_PER_BLOCK;
    agree_kernel<<<blocks, 256, 0, stream>>>(
        group_inputs, item_inputs, member_ids, member_lengths,
        user_table, item_table, group_table,
        att_w1, att_b1, att_w2, att_b2,
        pred_w1, pred_b1, pred_w2, pred_b2,
        out, B);
}

// Round 3
// 144.468 us; speedup vs baseline: 1.2099x; 1.0999x over previous
//
#include <hip/hip_runtime.h>
#include <math.h>

constexpr int MM = 50;    // members per group
constexpr int DD = 64;    // embedding dim
constexpr int HH = 16;    // attention hidden
constexpr int PH = 8;     // predict hidden
constexpr int WAVES_PER_BLOCK = 4;

// ============================================================================
// Kernel A: precompute U = user_table @ W1a  (nU x 16)
//           and        I = item_table @ W1b + b1 (nI x 16)
// thread-per-row GEMV; user blocks first, item blocks after (w1 ptr uniform
// per block so weight reads stay scalar).
// ============================================================================
__global__ __launch_bounds__(256) void precompute_kernel(
    const float* __restrict__ user_table,
    const float* __restrict__ item_table,
    const float* __restrict__ att_w1,   // [2D][H] row-major
    const float* __restrict__ att_b1,   // [H]
    float* __restrict__ U,
    float* __restrict__ I,
    int nU, int nI, int userBlocks)
{
    const bool isU = (int)blockIdx.x < userBlocks;
    const int row = isU ? ((int)blockIdx.x * 256 + (int)threadIdx.x)
                        : (((int)blockIdx.x - userBlocks) * 256 + (int)threadIdx.x);
    const int n = isU ? nU : nI;
    if (row >= n) return;

    const float* __restrict__ src = isU ? user_table : item_table;
    const float* __restrict__ w1  = isU ? att_w1 : (att_w1 + DD * HH); // uniform/block
    const float4* rp = (const float4*)(src + (size_t)row * DD);

    float acc[HH];
    #pragma unroll
    for (int j = 0; j < HH; ++j) acc[j] = isU ? 0.0f : att_b1[j];

    #pragma unroll 4
    for (int d4 = 0; d4 < DD / 4; ++d4) {
        const float4 x = rp[d4];
        const float* w = w1 + (size_t)(d4 * 4) * HH;   // uniform -> s_load
        #pragma unroll
        for (int j = 0; j < HH; ++j) {
            acc[j] = fmaf(x.x, w[0 * HH + j], acc[j]);
            acc[j] = fmaf(x.y, w[1 * HH + j], acc[j]);
            acc[j] = fmaf(x.z, w[2 * HH + j], acc[j]);
            acc[j] = fmaf(x.w, w[3 * HH + j], acc[j]);
        }
    }

    float4* o4 = (float4*)((isU ? U : I) + (size_t)row * HH);
    o4[0] = make_float4(acc[0],  acc[1],  acc[2],  acc[3]);
    o4[1] = make_float4(acc[4],  acc[5],  acc[6],  acc[7]);
    o4[2] = make_float4(acc[8],  acc[9],  acc[10], acc[11]);
    o4[3] = make_float4(acc[12], acc[13], acc[14], acc[15]);
}

// ============================================================================
// Kernel B: main — score from gathered U/I rows, softmax, pool, predict MLP
// ============================================================================
__global__ __launch_bounds__(256) void agree_main(
    const int* __restrict__ group_inputs,
    const int* __restrict__ item_inputs,
    const int* __restrict__ member_ids,
    const int* __restrict__ member_lengths,
    const float* __restrict__ user_table,
    const float* __restrict__ item_table,
    const float* __restrict__ group_table,
    const float* __restrict__ att_w2,   // [H]
    const float* __restrict__ att_b2,   // [1]
    const float* __restrict__ pred_w1,  // [3D][8]
    const float* __restrict__ pred_b1,  // [8]
    const float* __restrict__ pred_w2,  // [8]
    const float* __restrict__ pred_b2,  // [1]
    const float* __restrict__ U,        // [nU][16] precomputed
    const float* __restrict__ I,        // [nI][16] precomputed (b1 folded in)
    float* __restrict__ out,
    int B)
{
    __shared__ float2 lds_pair[WAVES_PER_BLOCK][MM]; // (softmax wt, id bits)

    const int lane = threadIdx.x & 63;
    const int wave = threadIdx.x >> 6;
    const int b = blockIdx.x * WAVES_PER_BLOCK + wave;
    if (b >= B) return;

    const int my_m = (lane < MM) ? lane : (MM - 1);
    const int my_id = member_ids[b * MM + my_m];            // coalesced
    const int item_idx = item_inputs[b];                    // uniform

    // ---- score: h[j] = U[my_id][j] + I[item][j]; score = relu(h)·w2 + b2
    const float4* up = (const float4*)(U + (size_t)my_id * HH); // 64B/lane gather
    const float4 u0 = up[0], u1 = up[1], u2 = up[2], u3 = up[3];
    const float* ip = I + (size_t)item_idx * HH;            // uniform -> s_load

    float score = att_b2[0];
    {
        const float uu[HH] = { u0.x,u0.y,u0.z,u0.w, u1.x,u1.y,u1.z,u1.w,
                               u2.x,u2.y,u2.z,u2.w, u3.x,u3.y,u3.z,u3.w };
        #pragma unroll
        for (int j = 0; j < HH; ++j)
            score = fmaf(fmaxf(uu[j] + ip[j], 0.0f), att_w2[j], score);
    }

    const int len = member_lengths[b];                      // uniform
    const bool valid = (lane < MM) && (lane <= len);
    score = valid ? score : -INFINITY;

    // ---- softmax over members (wave butterfly; member 0 always valid)
    float mx = score;
    #pragma unroll
    for (int off = 32; off > 0; off >>= 1) mx = fmaxf(mx, __shfl_xor(mx, off, 64));
    float e = valid ? __expf(score - mx) : 0.0f;
    float sum = e;
    #pragma unroll
    for (int off = 32; off > 0; off >>= 1) sum += __shfl_xor(sum, off, 64);
    if (lane < MM)
        lds_pair[wave][lane] = make_float2(e / sum, __int_as_float(my_id));
    __builtin_amdgcn_s_waitcnt(0);  // drain own-wave LDS writes (no barrier needed)

    // item embedding, lane-per-dim (needed for predict MLP)
    const float item_d = item_table[(size_t)item_idx * DD + lane];

    // ---- weighted pool, lane-per-dim, batched x4 for MLP-in-flight loads
    const int mcnt = (len < MM - 1 ? len : MM - 1) + 1;     // uniform in [1,50]
    float g = 0.0f;
    int m = 0;
    for (; m + 4 <= mcnt; m += 4) {
        const float2 q0 = lds_pair[wave][m + 0];
        const float2 q1 = lds_pair[wave][m + 1];
        const float2 q2 = lds_pair[wave][m + 2];
        const float2 q3 = lds_pair[wave][m + 3];
        const float x0 = user_table[(size_t)__float_as_int(q0.y) * DD + lane];
        const float x1 = user_table[(size_t)__float_as_int(q1.y) * DD + lane];
        const float x2 = user_table[(size_t)__float_as_int(q2.y) * DD + lane];
        const float x3 = user_table[(size_t)__float_as_int(q3.y) * DD + lane];
        g = fmaf(q0.x, x0, g);
        g = fmaf(q1.x, x1, g);
        g = fmaf(q2.x, x2, g);
        g = fmaf(q3.x, x3, g);
    }
    for (; m < mcnt; ++m) {
        const float2 q = lds_pair[wave][m];
        g = fmaf(q.x, user_table[(size_t)__float_as_int(q.y) * DD + lane], g);
    }
    const int gid = group_inputs[b];                        // uniform
    g += group_table[(size_t)gid * DD + lane];

    // ---- predict MLP: new_e = [g*item, g, item] (192 -> 8 -> 1)
    const float elem = g * item_d;
    float p[PH];
    {
        const float* pa = pred_w1 + (size_t)lane * PH;
        const float* pb = pred_w1 + (size_t)(DD + lane) * PH;
        const float* pc = pred_w1 + (size_t)(2 * DD + lane) * PH;
        #pragma unroll
        for (int j = 0; j < PH; ++j)
            p[j] = fmaf(elem, pa[j], fmaf(g, pb[j], item_d * pc[j]));
    }
    #pragma unroll
    for (int off = 32; off > 0; off >>= 1) {
        #pragma unroll
        for (int j = 0; j < PH; ++j) p[j] += __shfl_xor(p[j], off, 64);
    }

    if (lane == 0) {
        float acc = pred_b2[0];
        #pragma unroll
        for (int j = 0; j < PH; ++j)
            acc = fmaf(fmaxf(p[j] + pred_b1[j], 0.0f), pred_w2[j], acc);
        out[b] = 1.0f / (1.0f + __expf(-acc));
    }
}

// ============================================================================
// Fallback (round-2 kernel) if ws_size is too small for the precompute tables
// ============================================================================
__global__ __launch_bounds__(256) void agree_fallback(
    const int* __restrict__ group_inputs,
    const int* __restrict__ item_inputs,
    const int* __restrict__ member_ids,
    const int* __restrict__ member_lengths,
    const float* __restrict__ user_table,
    const float* __restrict__ item_table,
    const float* __restrict__ group_table,
    const float* __restrict__ att_w1,
    const float* __restrict__ att_b1,
    const float* __restrict__ att_w2,
    const float* __restrict__ att_b2,
    const float* __restrict__ pred_w1,
    const float* __restrict__ pred_b1,
    const float* __restrict__ pred_w2,
    const float* __restrict__ pred_b2,
    float* __restrict__ out,
    int B)
{
    __shared__ float lds_wt[WAVES_PER_BLOCK][MM];
    __shared__ int   lds_id[WAVES_PER_BLOCK][MM];

    const int lane = threadIdx.x & 63;
    const int wave = threadIdx.x >> 6;
    const int b = blockIdx.x * WAVES_PER_BLOCK + wave;
    if (b >= B) return;

    const int my_m = (lane < MM) ? lane : (MM - 1);
    const int my_id = member_ids[b * MM + my_m];
    if (lane < MM) lds_id[wave][lane] = my_id;

    const int item_idx = item_inputs[b];
    const float item_d = item_table[(size_t)item_idx * DD + lane];

    float h[HH];
    {
        const float* w1row = att_w1 + (size_t)(DD + lane) * HH;
        #pragma unroll
        for (int j = 0; j < HH; ++j) h[j] = item_d * w1row[j];
        #pragma unroll
        for (int off = 32; off > 0; off >>= 1) {
            #pragma unroll
            for (int j = 0; j < HH; ++j) h[j] += __shfl_xor(h[j], off, 64);
        }
        #pragma unroll
        for (int j = 0; j < HH; ++j) h[j] += att_b1[j];
    }

    const float* myrow = user_table + (size_t)my_id * DD;
    #pragma unroll 4
    for (int d4 = 0; d4 < DD / 4; ++d4) {
        const float4 x = ((const float4*)myrow)[d4];
        const float* w1d = att_w1 + (size_t)(d4 * 4) * HH;
        #pragma unroll
        for (int j = 0; j < HH; ++j) {
            h[j] = fmaf(x.x, w1d[0 * HH + j], h[j]);
            h[j] = fmaf(x.y, w1d[1 * HH + j], h[j]);
            h[j] = fmaf(x.z, w1d[2 * HH + j], h[j]);
            h[j] = fmaf(x.w, w1d[3 * HH + j], h[j]);
        }
    }

    float score = att_b2[0];
    #pragma unroll
    for (int j = 0; j < HH; ++j) score = fmaf(fmaxf(h[j], 0.0f), att_w2[j], score);

    const int len = member_lengths[b];
    const bool valid = (lane < MM) && (lane <= len);
    score = valid ? score : -INFINITY;

    float mx = score;
    #pragma unroll
    for (int off = 32; off > 0; off >>= 1) mx = fmaxf(mx, __shfl_xor(mx, off, 64));
    float e = valid ? __expf(score - mx) : 0.0f;
    float sum = e;
    #pragma unroll
    for (int off = 32; off > 0; off >>= 1) sum += __shfl_xor(sum, off, 64);
    if (lane < MM) lds_wt[wave][lane] = e / sum;
    __builtin_amdgcn_s_waitcnt(0);

    const int mcnt = (len < MM - 1 ? len : MM - 1) + 1;
    float g = 0.0f;
    #pragma unroll 2
    for (int m = 0; m < mcnt; ++m) {
        const float wm  = lds_wt[wave][m];
        const int   idm = lds_id[wave][m];
        g = fmaf(wm, user_table[(size_t)idm * DD + lane], g);
    }
    const int gid = group_inputs[b];
    g += group_table[(size_t)gid * DD + lane];

    const float elem = g * item_d;
    float p[PH];
    {
        const float* pa = pred_w1 + (size_t)lane * PH;
        const float* pb = pred_w1 + (size_t)(DD + lane) * PH;
        const float* pc = pred_w1 + (size_t)(2 * DD + lane) * PH;
        #pragma unroll
        for (int j = 0; j < PH; ++j)
            p[j] = fmaf(elem, pa[j], fmaf(g, pb[j], item_d * pc[j]));
    }
    #pragma unroll
    for (int off = 32; off > 0; off >>= 1) {
        #pragma unroll
        for (int j = 0; j < PH; ++j) p[j] += __shfl_xor(p[j], off, 64);
    }

    if (lane == 0) {
        float acc = pred_b2[0];
        #pragma unroll
        for (int j = 0; j < PH; ++j)
            acc = fmaf(fmaxf(p[j] + pred_b1[j], 0.0f), pred_w2[j], acc);
        out[b] = 1.0f / (1.0f + __expf(-acc));
    }
}

extern "C" void kernel_launch(void* const* d_in, const int* in_sizes, int n_in,
                              void* d_out, int out_size, void* d_ws, size_t ws_size,
                              hipStream_t stream) {
    const int*   group_inputs   = (const int*)d_in[0];
    const int*   item_inputs    = (const int*)d_in[1];
    const int*   member_ids     = (const int*)d_in[2];
    const int*   member_lengths = (const int*)d_in[3];
    const float* user_table     = (const float*)d_in[4];
    const float* item_table     = (const float*)d_in[5];
    const float* group_table    = (const float*)d_in[6];
    const float* att_w1         = (const float*)d_in[7];
    const float* att_b1         = (const float*)d_in[8];
    const float* att_w2         = (const float*)d_in[9];
    const float* att_b2         = (const float*)d_in[10];
    const float* pred_w1        = (const float*)d_in[11];
    const float* pred_b1        = (const float*)d_in[12];
    const float* pred_w2        = (const float*)d_in[13];
    const float* pred_b2        = (const float*)d_in[14];
    float* out = (float*)d_out;

    const int B  = in_sizes[0];
    const int nU = in_sizes[4] / DD;
    const int nI = in_sizes[5] / DD;
    const size_t need = (size_t)(nU + nI) * HH * sizeof(float);
    const int blocks = (B + WAVES_PER_BLOCK - 1) / WAVES_PER_BLOCK;

    if (ws_size >= need) {
        float* U = (float*)d_ws;
        float* I = U + (size_t)nU * HH;
        const int userBlocks = (nU + 255) / 256;
        const int itemBlocks = (nI + 255) / 256;
        precompute_kernel<<<userBlocks + itemBlocks, 256, 0, stream>>>(
            user_table, item_table, att_w1, att_b1, U, I, nU, nI, userBlocks);
        agree_main<<<blocks, 256, 0, stream>>>(
            group_inputs, item_inputs, member_ids, member_lengths,
            user_table, item_table, group_table,
            att_w2, att_b2, pred_w1, pred_b1, pred_w2, pred_b2,
            U, I, out, B);
    } else {
        agree_fallback<<<blocks, 256, 0, stream>>>(
            group_inputs, item_inputs, member_ids, member_lengths,
            user_table, item_table, group_table,
            att_w1, att_b1, att_w2, att_b2,
            pred_w1, pred_b1, pred_w2, pred_b2,
            out, B);
    }
}